// Round 3
// baseline (896.115 us; speedup 1.0000x reference)
//
#include <hip/hip_runtime.h>

#define NM 50000
#define HD 128
#define KNEI 8
#define BM 64
#define NT 512
#define LDA 132
#define NH ((size_t)NM * (size_t)HD)

__device__ __forceinline__ float sigm_f(float x) {
    return __builtin_amdgcn_rcpf(1.0f + __expf(-x));
}
__device__ __forceinline__ float tanh_f(float x) {
    return 2.0f * sigm_f(2.0f * x) - 1.0f;
}

// C[m][g] = epilogue( sum_e A[m][e] * W[g][woff+e] ), e in [0,128)
// MODE 0: C = A@W.T + bias
// MODE 1: C = sigmoid(pre + A@W.T)
// MODE 2: ph = tanh(pre + A@W.T); C = mask*((1-z)*sumh + z*ph)
template<int MODE>
__global__ __launch_bounds__(NT, 1)
void dgru_gemm(const float* __restrict__ A, const float* __restrict__ W,
               int ldw, int woff,
               const float* __restrict__ bias, const float* __restrict__ pre,
               const float* __restrict__ zbuf, const float* __restrict__ sumh,
               float* __restrict__ C)
{
    __shared__ float Wt[HD][HD];   // Wt[e][g] = W[g][woff+e]   (64 KB)
    __shared__ float As[BM][LDA];  // padded rows -> conflict-free writes (33.8 KB)
    const int tid  = threadIdx.x;
    const int row0 = blockIdx.x * BM;

    // ---- stage W transposed: thread t -> row g=t/4, 32-float chunk (t&3)*32
    {
        const int g  = tid >> 2;
        const int e0 = (tid & 3) << 5;
        const float* wp = W + (size_t)g * ldw + woff + e0;
        #pragma unroll
        for (int j = 0; j < 32; j += 4) {
            const float4 w = *(const float4*)(wp + j);
            Wt[e0 + j + 0][g] = w.x;
            Wt[e0 + j + 1][g] = w.y;
            Wt[e0 + j + 2][g] = w.z;
            Wt[e0 + j + 3][g] = w.w;
        }
    }
    // ---- stage A tile: thread t -> row t/8, 16-float chunk (t&7)*16
    {
        const int r  = tid >> 3;
        const int e0 = (tid & 7) << 4;
        int gr = row0 + r; if (gr >= NM) gr = NM - 1;   // clamp; OOB rows never stored
        const float* ap = A + (size_t)gr * HD + e0;
        #pragma unroll
        for (int j = 0; j < 16; j += 4)
            *(float4*)&As[r][e0 + j] = *(const float4*)(ap + j);
    }
    __syncthreads();

    // per-thread tile: 2 rows x (4 cols @ ca, 4 cols @ cb)
    const int l  = tid & 15;
    const int r0 = (tid >> 4) << 1;    // 0..62
    const int ca = l << 2;             // 0..60
    const int cb = 64 + (l << 2);      // 64..124

    float acc[2][8];
    #pragma unroll
    for (int i = 0; i < 2; ++i)
        #pragma unroll
        for (int j = 0; j < 8; ++j) acc[i][j] = 0.0f;

    #pragma unroll 4
    for (int e = 0; e < HD; e += 4) {
        float a0v[4], a1v[4];
        *(float4*)a0v = *(const float4*)&As[r0][e];
        *(float4*)a1v = *(const float4*)&As[r0 + 1][e];
        #pragma unroll
        for (int j = 0; j < 4; ++j) {
            const float4 wa = *(const float4*)&Wt[e + j][ca];
            const float4 wb = *(const float4*)&Wt[e + j][cb];
            acc[0][0] = fmaf(a0v[j], wa.x, acc[0][0]);
            acc[0][1] = fmaf(a0v[j], wa.y, acc[0][1]);
            acc[0][2] = fmaf(a0v[j], wa.z, acc[0][2]);
            acc[0][3] = fmaf(a0v[j], wa.w, acc[0][3]);
            acc[0][4] = fmaf(a0v[j], wb.x, acc[0][4]);
            acc[0][5] = fmaf(a0v[j], wb.y, acc[0][5]);
            acc[0][6] = fmaf(a0v[j], wb.z, acc[0][6]);
            acc[0][7] = fmaf(a0v[j], wb.w, acc[0][7]);
            acc[1][0] = fmaf(a1v[j], wa.x, acc[1][0]);
            acc[1][1] = fmaf(a1v[j], wa.y, acc[1][1]);
            acc[1][2] = fmaf(a1v[j], wa.z, acc[1][2]);
            acc[1][3] = fmaf(a1v[j], wa.w, acc[1][3]);
            acc[1][4] = fmaf(a1v[j], wb.x, acc[1][4]);
            acc[1][5] = fmaf(a1v[j], wb.y, acc[1][5]);
            acc[1][6] = fmaf(a1v[j], wb.z, acc[1][6]);
            acc[1][7] = fmaf(a1v[j], wb.w, acc[1][7]);
        }
    }

    float4 bva = make_float4(0.f, 0.f, 0.f, 0.f);
    float4 bvb = make_float4(0.f, 0.f, 0.f, 0.f);
    if (MODE == 0 && bias) { bva = *(const float4*)&bias[ca]; bvb = *(const float4*)&bias[cb]; }

    #pragma unroll
    for (int i = 0; i < 2; ++i) {
        const int r = row0 + r0 + i;
        if (r >= NM) continue;
        #pragma unroll
        for (int half = 0; half < 2; ++half) {
            const int c = half ? cb : ca;
            const float* ac = &acc[i][half * 4];
            const size_t off = (size_t)r * HD + c;
            float4 o;
            if (MODE == 0) {
                const float4 bv = half ? bvb : bva;
                o = make_float4(ac[0] + bv.x, ac[1] + bv.y, ac[2] + bv.z, ac[3] + bv.w);
            } else if (MODE == 1) {
                const float4 p = *(const float4*)&pre[off];
                o = make_float4(sigm_f(p.x + ac[0]), sigm_f(p.y + ac[1]),
                                sigm_f(p.z + ac[2]), sigm_f(p.w + ac[3]));
            } else {
                const float4 p  = *(const float4*)&pre[off];
                const float4 z4 = *(const float4*)&zbuf[off];
                const float4 s4 = *(const float4*)&sumh[off];
                o = make_float4((1.0f - z4.x) * s4.x + z4.x * tanh_f(p.x + ac[0]),
                                (1.0f - z4.y) * s4.y + z4.y * tanh_f(p.y + ac[1]),
                                (1.0f - z4.z) * s4.z + z4.z * tanh_f(p.z + ac[2]),
                                (1.0f - z4.w) * s4.w + z4.w * tanh_f(p.w + ac[3]));
                if (r == 0) o = make_float4(0.f, 0.f, 0.f, 0.f);  // padding-message mask
            }
            *(float4*)&C[off] = o;
        }
    }
}

// it==0: h = sigmoid(pre_z) * tanh(pre_hf), row 0 zeroed. One float4 per thread.
__global__ __launch_bounds__(256)
void dgru_h0(const float* __restrict__ pz, const float* __restrict__ phf,
             float* __restrict__ h)
{
    const size_t i = (size_t)blockIdx.x * 256 + threadIdx.x;   // float4 index
    const float4 z = ((const float4*)pz)[i];
    const float4 p = ((const float4*)phf)[i];
    float4 o = make_float4(sigm_f(z.x) * tanh_f(p.x), sigm_f(z.y) * tanh_f(p.y),
                           sigm_f(z.z) * tanh_f(p.z), sigm_f(z.w) * tanh_f(p.w));
    if ((i >> 5) == 0) o = make_float4(0.f, 0.f, 0.f, 0.f);    // message 0 = padding
    ((float4*)h)[i] = o;
}

// Per message n: sum_h = sum_k h[bg[n][k]]; sum_g = sum_k sigmoid(pre_r+Uh[bg[n][k]])*h[..]
__global__ __launch_bounds__(256)
void dgru_gather(const float* __restrict__ h, const float* __restrict__ Uh,
                 const int* __restrict__ bgraph, const float* __restrict__ pre_r,
                 float* __restrict__ sumh, float* __restrict__ sumg)
{
    const int tid = threadIdx.x;
    const int n   = blockIdx.x * 8 + (tid >> 5);
    const int d0  = (tid & 31) << 2;
    if (n >= NM) return;

    int idx[KNEI];
    {
        const int4* bg = (const int4*)(bgraph + (size_t)n * KNEI);
        const int4 b0 = bg[0], b1 = bg[1];
        idx[0] = b0.x; idx[1] = b0.y; idx[2] = b0.z; idx[3] = b0.w;
        idx[4] = b1.x; idx[5] = b1.y; idx[6] = b1.z; idx[7] = b1.w;
    }
    const float4 pr = *(const float4*)&pre_r[(size_t)n * HD + d0];
    float4 sh = make_float4(0.f, 0.f, 0.f, 0.f);
    float4 sg = make_float4(0.f, 0.f, 0.f, 0.f);

    #pragma unroll
    for (int k = 0; k < KNEI; ++k) {
        const size_t o = (size_t)idx[k] * HD + d0;
        const float4 hv = *(const float4*)&h[o];
        const float4 uv = *(const float4*)&Uh[o];
        sh.x += hv.x; sh.y += hv.y; sh.z += hv.z; sh.w += hv.w;
        sg.x = fmaf(sigm_f(pr.x + uv.x), hv.x, sg.x);
        sg.y = fmaf(sigm_f(pr.y + uv.y), hv.y, sg.y);
        sg.z = fmaf(sigm_f(pr.z + uv.z), hv.z, sg.z);
        sg.w = fmaf(sigm_f(pr.w + uv.w), hv.w, sg.w);
    }
    const size_t o = (size_t)n * HD + d0;
    *(float4*)&sumh[o] = sh;
    *(float4*)&sumg[o] = sg;
}

extern "C" void kernel_launch(void* const* d_in, const int* in_sizes, int n_in,
                              void* d_out, int out_size, void* d_ws, size_t ws_size,
                              hipStream_t stream) {
    const float* fmess  = (const float*)d_in[0];
    const int*   bgraph = (const int*)  d_in[1];
    const float* W_z    = (const float*)d_in[2];
    const float* b_z    = (const float*)d_in[3];
    const float* W_r    = (const float*)d_in[4];
    const float* U_r    = (const float*)d_in[5];
    const float* b_Ur   = (const float*)d_in[6];
    const float* W_h    = (const float*)d_in[7];
    const float* b_h    = (const float*)d_in[8];

    float* ws     = (float*)d_ws;
    float* pre_z  = ws;            // fmess@Wz1.T + b_z
    float* pre_r  = ws + NH;       // fmess@W_r.T
    float* pre_hf = ws + 2 * NH;   // fmess@Wh1.T + b_h
    float* Uh     = ws + 3 * NH;   // h@U_r.T + b_Ur; reused as z-buffer
    float* sum_h  = ws + 4 * NH;
    float* sum_g  = ws + 5 * NH;
    float* h      = (float*)d_out; // h lives in d_out across iterations
    // requires ws_size >= 6*NH*4 = 153.6 MB (verified OK in R2)

    const dim3 gblk(NT);
    const dim3 ggrid((NM + BM - 1) / BM);   // 782
    const dim3 sgrid(NM / 8);               // 6250

    // Loop-invariant precompute (fmess halves of the concat matmuls; biases folded)
    dgru_gemm<0><<<ggrid, gblk, 0, stream>>>(fmess, W_z, 2 * HD, 0, b_z, nullptr, nullptr, nullptr, pre_z);
    dgru_gemm<0><<<ggrid, gblk, 0, stream>>>(fmess, W_r, HD,     0, nullptr, nullptr, nullptr, nullptr, pre_r);
    dgru_gemm<0><<<ggrid, gblk, 0, stream>>>(fmess, W_h, 2 * HD, 0, b_h, nullptr, nullptr, nullptr, pre_hf);

    // it = 0 collapses to elementwise (h_prev = 0)
    dgru_h0<<<dim3(6250), dim3(256), 0, stream>>>(pre_z, pre_hf, h);

    for (int it = 1; it < 5; ++it) {
        dgru_gemm<0><<<ggrid, gblk, 0, stream>>>(h, U_r, HD, 0, b_Ur, nullptr, nullptr, nullptr, Uh);
        dgru_gather<<<sgrid, dim3(256), 0, stream>>>(h, Uh, bgraph, pre_r, sum_h, sum_g);
        // z = sigmoid(pre_z + sum_h @ Wz2.T); stored in Uh buffer (dead after gather)
        dgru_gemm<1><<<ggrid, gblk, 0, stream>>>(sum_h, W_z, 2 * HD, HD, nullptr, pre_z, nullptr, nullptr, Uh);
        // ph = tanh(pre_hf + sum_g @ Wh2.T); h = mask*((1-z)*sum_h + z*ph)
        dgru_gemm<2><<<ggrid, gblk, 0, stream>>>(sum_g, W_h, 2 * HD, HD, nullptr, pre_hf, Uh, sum_h, h);
    }
}

// Round 5
// 829.476 us; speedup vs baseline: 1.0803x; 1.0803x over previous
//
#include <hip/hip_runtime.h>

#define NM 50000
#define HD 128
#define BM 128
#define LDA 132
#define KNEI 8
#define NTH 256
#define NBLK ((NM + BM - 1) / BM)   // 391
#define NH ((size_t)NM * (size_t)HD)

__device__ __forceinline__ float sigm_f(float x) {
    return __builtin_amdgcn_rcpf(1.0f + __expf(-x));
}
__device__ __forceinline__ float tanh_f(float x) {
    return 2.0f * sigm_f(2.0f * x) - 1.0f;
}

// ---------- shared-tile helpers (caller handles __syncthreads) ----------

// Wt[e][g] = W[g][woff+e]  (transposed stage; 2-way bank alias on writes = free)
__device__ __forceinline__ void stage_W(const float* __restrict__ W, int ldw, int woff,
                                        float (*Wt)[HD], int tid)
{
    const int g  = tid >> 1;           // 0..127
    const int e0 = (tid & 1) << 6;     // 0 or 64
    const float* wp = W + (size_t)g * ldw + woff + e0;
    #pragma unroll
    for (int j = 0; j < 64; j += 4) {
        const float4 w = *(const float4*)(wp + j);
        Wt[e0 + j + 0][g] = w.x;
        Wt[e0 + j + 1][g] = w.y;
        Wt[e0 + j + 2][g] = w.z;
        Wt[e0 + j + 3][g] = w.w;
    }
}

// As[r][:] = A[row0+r][:], rows clamped; row-per-lane -> conflict-free LDS writes
__device__ __forceinline__ void stage_A(const float* A, int row0,
                                        float (*As)[LDA], int tid)
{
    const int r  = tid & 127;
    const int c0 = (tid >> 7) << 6;    // 0 or 64
    int gr = row0 + r; if (gr >= NM) gr = NM - 1;
    const float* ap = A + (size_t)gr * HD + c0;
    #pragma unroll
    for (int j = 0; j < 64; j += 4)
        *(float4*)&As[r][c0 + j] = *(const float4*)(ap + j);
}

// acc[i][c] += sum_e As[r0+i][e] * Wt[e][ca+c]   (8 rows x 8 cols per thread)
__device__ __forceinline__ void gemm_tile(const float (*As)[LDA], const float (*Wt)[HD],
                                          int r0, int ca, float (&acc)[8][8])
{
    for (int e = 0; e < HD; e += 4) {
        float av[8][4];
        #pragma unroll
        for (int i = 0; i < 8; ++i)
            *(float4*)av[i] = *(const float4*)&As[r0 + i][e];
        #pragma unroll
        for (int j = 0; j < 4; ++j) {
            const float4 wa = *(const float4*)&Wt[e + j][ca];
            const float4 wb = *(const float4*)&Wt[e + j][ca + 4];
            #pragma unroll
            for (int i = 0; i < 8; ++i) {
                const float a = av[i][j];
                acc[i][0] = fmaf(a, wa.x, acc[i][0]);
                acc[i][1] = fmaf(a, wa.y, acc[i][1]);
                acc[i][2] = fmaf(a, wa.z, acc[i][2]);
                acc[i][3] = fmaf(a, wa.w, acc[i][3]);
                acc[i][4] = fmaf(a, wb.x, acc[i][4]);
                acc[i][5] = fmaf(a, wb.y, acc[i][5]);
                acc[i][6] = fmaf(a, wb.z, acc[i][6]);
                acc[i][7] = fmaf(a, wb.w, acc[i][7]);
            }
        }
    }
}

#define ZERO_ACC(acc) { _Pragma("unroll") for (int i_ = 0; i_ < 8; ++i_) \
                        _Pragma("unroll") for (int j_ = 0; j_ < 8; ++j_) acc[i_][j_] = 0.0f; }

// ---------- pre: pre_z / pre_r / pre_hf GEMMs + h0 + Uh0, one kernel ----------
__global__ __launch_bounds__(NTH, 1)
void dgru_pre(const float* __restrict__ fmess,
              const float* __restrict__ Wz, const float* __restrict__ bz,
              const float* __restrict__ Wr,
              const float* __restrict__ Wh, const float* __restrict__ bh,
              const float* __restrict__ Ur, const float* __restrict__ bur,
              float* __restrict__ pre_z, float* __restrict__ pre_r,
              float* __restrict__ pre_hf, float* h, float* __restrict__ Uh)
{
    __shared__ float Wt[HD][HD];     // 64 KB
    __shared__ float As[BM][LDA];    // 67.6 KB
    const int tid  = threadIdx.x;
    const int row0 = blockIdx.x * BM;
    const int ca   = (tid & 15) << 3;
    const int r0   = (tid >> 4) << 3;

    stage_A(fmess, row0, As, tid);

    float zres[8][8];   // sigmoid-arg of z kept in regs for phase 4

    // ---- phase 1: pre_z = fmess @ Wz[:, :128].T + bz
    stage_W(Wz, 2 * HD, 0, Wt, tid);
    __syncthreads();
    {
        float acc[8][8]; ZERO_ACC(acc);
        gemm_tile(As, Wt, r0, ca, acc);
        const float4 b0 = *(const float4*)&bz[ca];
        const float4 b1 = *(const float4*)&bz[ca + 4];
        #pragma unroll
        for (int i = 0; i < 8; ++i) {
            const int r = row0 + r0 + i;
            zres[i][0] = acc[i][0] + b0.x; zres[i][1] = acc[i][1] + b0.y;
            zres[i][2] = acc[i][2] + b0.z; zres[i][3] = acc[i][3] + b0.w;
            zres[i][4] = acc[i][4] + b1.x; zres[i][5] = acc[i][5] + b1.y;
            zres[i][6] = acc[i][6] + b1.z; zres[i][7] = acc[i][7] + b1.w;
            if (r < NM) {
                *(float4*)&pre_z[(size_t)r * HD + ca]     = *(float4*)&zres[i][0];
                *(float4*)&pre_z[(size_t)r * HD + ca + 4] = *(float4*)&zres[i][4];
            }
        }
    }
    __syncthreads();

    // ---- phase 2: pre_r = fmess @ Wr.T
    stage_W(Wr, HD, 0, Wt, tid);
    __syncthreads();
    {
        float acc[8][8]; ZERO_ACC(acc);
        gemm_tile(As, Wt, r0, ca, acc);
        #pragma unroll
        for (int i = 0; i < 8; ++i) {
            const int r = row0 + r0 + i;
            if (r < NM) {
                *(float4*)&pre_r[(size_t)r * HD + ca]     = *(float4*)&acc[i][0];
                *(float4*)&pre_r[(size_t)r * HD + ca + 4] = *(float4*)&acc[i][4];
            }
        }
    }
    __syncthreads();

    // ---- phase 3+4: pre_hf = fmess @ Wh[:, :128].T + bh ; h0 = sigm(zres)*tanh(pre_hf)
    stage_W(Wh, 2 * HD, 0, Wt, tid);
    __syncthreads();
    {
        float acc[8][8]; ZERO_ACC(acc);
        gemm_tile(As, Wt, r0, ca, acc);
        const float4 b0 = *(const float4*)&bh[ca];
        const float4 b1 = *(const float4*)&bh[ca + 4];
        #pragma unroll
        for (int i = 0; i < 8; ++i) {
            const int r = row0 + r0 + i;
            float p[8];
            p[0] = acc[i][0] + b0.x; p[1] = acc[i][1] + b0.y;
            p[2] = acc[i][2] + b0.z; p[3] = acc[i][3] + b0.w;
            p[4] = acc[i][4] + b1.x; p[5] = acc[i][5] + b1.y;
            p[6] = acc[i][6] + b1.z; p[7] = acc[i][7] + b1.w;
            if (r < NM) {
                *(float4*)&pre_hf[(size_t)r * HD + ca]     = *(float4*)&p[0];
                *(float4*)&pre_hf[(size_t)r * HD + ca + 4] = *(float4*)&p[4];
                float ho[8];
                #pragma unroll
                for (int j = 0; j < 8; ++j)
                    ho[j] = (r == 0) ? 0.0f : sigm_f(zres[i][j]) * tanh_f(p[j]);
                *(float4*)&h[(size_t)r * HD + ca]     = *(float4*)&ho[0];
                *(float4*)&h[(size_t)r * HD + ca + 4] = *(float4*)&ho[4];
            }
        }
    }
    __syncthreads();   // h stores visible block-wide before re-read

    // ---- phase 5: Uh = h @ Ur.T + bur   (this block's rows only)
    stage_W(Ur, HD, 0, Wt, tid);
    stage_A(h, row0, As, tid);
    __syncthreads();
    {
        float acc[8][8]; ZERO_ACC(acc);
        gemm_tile(As, Wt, r0, ca, acc);
        const float4 b0 = *(const float4*)&bur[ca];
        const float4 b1 = *(const float4*)&bur[ca + 4];
        #pragma unroll
        for (int i = 0; i < 8; ++i) {
            const int r = row0 + r0 + i;
            if (r < NM) {
                float o[8];
                o[0] = acc[i][0] + b0.x; o[1] = acc[i][1] + b0.y;
                o[2] = acc[i][2] + b0.z; o[3] = acc[i][3] + b0.w;
                o[4] = acc[i][4] + b1.x; o[5] = acc[i][5] + b1.y;
                o[6] = acc[i][6] + b1.z; o[7] = acc[i][7] + b1.w;
                *(float4*)&Uh[(size_t)r * HD + ca]     = *(float4*)&o[0];
                *(float4*)&Uh[(size_t)r * HD + ca + 4] = *(float4*)&o[4];
            }
        }
    }
}

// ---------- zhu: z-GEMM (z in regs) + h-GEMM/GRU-update + next-iter Uh GEMM ----------
__global__ __launch_bounds__(NTH, 1)
void dgru_zhu(const float* __restrict__ sum_h, const float* __restrict__ sum_g,
              const float* __restrict__ pre_z, const float* __restrict__ pre_hf,
              const float* __restrict__ Wz, const float* __restrict__ Wh,
              const float* __restrict__ Ur, const float* __restrict__ bur,
              float* h, float* __restrict__ Uh, int do_uh)
{
    __shared__ float Wt[HD][HD];
    __shared__ float As[BM][LDA];
    const int tid  = threadIdx.x;
    const int row0 = blockIdx.x * BM;
    const int ca   = (tid & 15) << 3;
    const int r0   = (tid >> 4) << 3;

    // ---- phase 1: z = sigmoid(pre_z + sum_h @ Wz[:,128:].T)  (registers only)
    stage_W(Wz, 2 * HD, HD, Wt, tid);
    stage_A(sum_h, row0, As, tid);
    __syncthreads();
    float zres[8][8];
    {
        float acc[8][8]; ZERO_ACC(acc);
        gemm_tile(As, Wt, r0, ca, acc);
        #pragma unroll
        for (int i = 0; i < 8; ++i) {
            const int r = row0 + r0 + i;
            const size_t off = (size_t)(r < NM ? r : NM - 1) * HD + ca;
            const float4 p0 = *(const float4*)&pre_z[off];
            const float4 p1 = *(const float4*)&pre_z[off + 4];
            zres[i][0] = sigm_f(p0.x + acc[i][0]); zres[i][1] = sigm_f(p0.y + acc[i][1]);
            zres[i][2] = sigm_f(p0.z + acc[i][2]); zres[i][3] = sigm_f(p0.w + acc[i][3]);
            zres[i][4] = sigm_f(p1.x + acc[i][4]); zres[i][5] = sigm_f(p1.y + acc[i][5]);
            zres[i][6] = sigm_f(p1.z + acc[i][6]); zres[i][7] = sigm_f(p1.w + acc[i][7]);
        }
    }
    __syncthreads();

    // ---- phase 2: ph = tanh(pre_hf + sum_g @ Wh[:,128:].T); h = mask*((1-z)*sum_h + z*ph)
    stage_W(Wh, 2 * HD, HD, Wt, tid);
    stage_A(sum_g, row0, As, tid);
    __syncthreads();
    {
        float acc[8][8]; ZERO_ACC(acc);
        gemm_tile(As, Wt, r0, ca, acc);
        #pragma unroll
        for (int i = 0; i < 8; ++i) {
            const int r = row0 + r0 + i;
            if (r >= NM) continue;
            const size_t off = (size_t)r * HD + ca;
            const float4 p0 = *(const float4*)&pre_hf[off];
            const float4 p1 = *(const float4*)&pre_hf[off + 4];
            const float4 s0 = *(const float4*)&sum_h[off];
            const float4 s1 = *(const float4*)&sum_h[off + 4];
            float o[8];
            o[0] = (1.0f - zres[i][0]) * s0.x + zres[i][0] * tanh_f(p0.x + acc[i][0]);
            o[1] = (1.0f - zres[i][1]) * s0.y + zres[i][1] * tanh_f(p0.y + acc[i][1]);
            o[2] = (1.0f - zres[i][2]) * s0.z + zres[i][2] * tanh_f(p0.z + acc[i][2]);
            o[3] = (1.0f - zres[i][3]) * s0.w + zres[i][3] * tanh_f(p0.w + acc[i][3]);
            o[4] = (1.0f - zres[i][4]) * s1.x + zres[i][4] * tanh_f(p1.x + acc[i][4]);
            o[5] = (1.0f - zres[i][5]) * s1.y + zres[i][5] * tanh_f(p1.y + acc[i][5]);
            o[6] = (1.0f - zres[i][6]) * s1.z + zres[i][6] * tanh_f(p1.z + acc[i][6]);
            o[7] = (1.0f - zres[i][7]) * s1.w + zres[i][7] * tanh_f(p1.w + acc[i][7]);
            if (r == 0) {
                for (int j = 0; j < 8; ++j) o[j] = 0.0f;
            }
            *(float4*)&h[off]     = *(float4*)&o[0];
            *(float4*)&h[off + 4] = *(float4*)&o[4];
        }
    }

    if (!do_uh) return;
    __syncthreads();   // h stores visible block-wide before re-read

    // ---- phase 3: Uh = h @ Ur.T + bur
    stage_W(Ur, HD, 0, Wt, tid);
    stage_A(h, row0, As, tid);
    __syncthreads();
    {
        float acc[8][8]; ZERO_ACC(acc);
        gemm_tile(As, Wt, r0, ca, acc);
        const float4 b0 = *(const float4*)&bur[ca];
        const float4 b1 = *(const float4*)&bur[ca + 4];
        #pragma unroll
        for (int i = 0; i < 8; ++i) {
            const int r = row0 + r0 + i;
            if (r >= NM) continue;
            float o[8];
            o[0] = acc[i][0] + b0.x; o[1] = acc[i][1] + b0.y;
            o[2] = acc[i][2] + b0.z; o[3] = acc[i][3] + b0.w;
            o[4] = acc[i][4] + b1.x; o[5] = acc[i][5] + b1.y;
            o[6] = acc[i][6] + b1.z; o[7] = acc[i][7] + b1.w;
            *(float4*)&Uh[(size_t)r * HD + ca]     = *(float4*)&o[0];
            *(float4*)&Uh[(size_t)r * HD + ca + 4] = *(float4*)&o[4];
        }
    }
}

// ---------- gather: all 16 row-loads in flight before reduction ----------
__global__ __launch_bounds__(256)
void dgru_gather(const float* __restrict__ h, const float* __restrict__ Uh,
                 const int* __restrict__ bgraph, const float* __restrict__ pre_r,
                 float* __restrict__ sumh, float* __restrict__ sumg)
{
    const int tid = threadIdx.x;
    const int n   = blockIdx.x * 8 + (tid >> 5);   // grid covers NM exactly
    const int d0  = (tid & 31) << 2;

    const int4* bg = (const int4*)(bgraph + (size_t)n * KNEI);
    const int4 b0 = bg[0], b1 = bg[1];
    const int idx[KNEI] = {b0.x, b0.y, b0.z, b0.w, b1.x, b1.y, b1.z, b1.w};

    float4 hv[KNEI], uv[KNEI];
    #pragma unroll
    for (int k = 0; k < KNEI; ++k)
        hv[k] = *(const float4*)&h[(size_t)idx[k] * HD + d0];
    #pragma unroll
    for (int k = 0; k < KNEI; ++k)
        uv[k] = *(const float4*)&Uh[(size_t)idx[k] * HD + d0];
    const float4 pr = *(const float4*)&pre_r[(size_t)n * HD + d0];

    float4 sh = make_float4(0.f, 0.f, 0.f, 0.f);
    float4 sg = make_float4(0.f, 0.f, 0.f, 0.f);
    #pragma unroll
    for (int k = 0; k < KNEI; ++k) {            // accumulation order preserved
        sh.x += hv[k].x; sh.y += hv[k].y; sh.z += hv[k].z; sh.w += hv[k].w;
        sg.x = fmaf(sigm_f(pr.x + uv[k].x), hv[k].x, sg.x);
        sg.y = fmaf(sigm_f(pr.y + uv[k].y), hv[k].y, sg.y);
        sg.z = fmaf(sigm_f(pr.z + uv[k].z), hv[k].z, sg.z);
        sg.w = fmaf(sigm_f(pr.w + uv[k].w), hv[k].w, sg.w);
    }
    const size_t o = (size_t)n * HD + d0;
    *(float4*)&sumh[o] = sh;
    *(float4*)&sumg[o] = sg;
}

extern "C" void kernel_launch(void* const* d_in, const int* in_sizes, int n_in,
                              void* d_out, int out_size, void* d_ws, size_t ws_size,
                              hipStream_t stream) {
    const float* fmess  = (const float*)d_in[0];
    const int*   bgraph = (const int*)  d_in[1];
    const float* W_z    = (const float*)d_in[2];
    const float* b_z    = (const float*)d_in[3];
    const float* W_r    = (const float*)d_in[4];
    const float* U_r    = (const float*)d_in[5];
    const float* b_Ur   = (const float*)d_in[6];
    const float* W_h    = (const float*)d_in[7];
    const float* b_h    = (const float*)d_in[8];

    float* ws     = (float*)d_ws;
    float* pre_z  = ws;
    float* pre_r  = ws + NH;
    float* pre_hf = ws + 2 * NH;
    float* Uh     = ws + 3 * NH;
    float* sum_h  = ws + 4 * NH;
    float* sum_g  = ws + 5 * NH;
    float* h      = (float*)d_out;
    // requires ws_size >= 6*NH*4 = 153.6 MB (OK per R2/R3)

    dgru_pre<<<dim3(NBLK), dim3(NTH), 0, stream>>>(
        fmess, W_z, b_z, W_r, W_h, b_h, U_r, b_Ur,
        pre_z, pre_r, pre_hf, h, Uh);

    for (int it = 1; it < 5; ++it) {
        dgru_gather<<<dim3(NM / 8), dim3(256), 0, stream>>>(h, Uh, bgraph, pre_r, sum_h, sum_g);
        dgru_zhu<<<dim3(NBLK), dim3(NTH), 0, stream>>>(
            sum_h, sum_g, pre_z, pre_hf, W_z, W_h, U_r, b_Ur,
            h, Uh, (it < 4) ? 1 : 0);
    }
}

// Round 6
// 393.938 us; speedup vs baseline: 2.2748x; 2.1056x over previous
//
#include <hip/hip_runtime.h>
#include <hip/hip_bf16.h>

#define NM 50000
#define HD 128
#define KNEI 8
#define BM 64
#define SPAD 136
#define NBLK ((NM + BM - 1) / BM)   // 782
#define NH ((size_t)NM * (size_t)HD)

typedef float  fx4   __attribute__((ext_vector_type(4)));
typedef short  s16x8 __attribute__((ext_vector_type(8)));
typedef short  s16x4 __attribute__((ext_vector_type(4)));

__device__ __forceinline__ float sigm_f(float x) {
    return __builtin_amdgcn_rcpf(1.0f + __expf(-x));
}
__device__ __forceinline__ float tanh_f(float x) {
    return 2.0f * sigm_f(2.0f * x) - 1.0f;
}
__device__ __forceinline__ unsigned short f2b(float f) {
    __hip_bfloat16 h = __float2bfloat16(f);
    return __builtin_bit_cast(unsigned short, h);
}
__device__ __forceinline__ float b2f(unsigned short u) {
    __hip_bfloat16 h = __builtin_bit_cast(__hip_bfloat16, u);
    return __bfloat162float(h);
}

#define MFMA16(a, b, c) __builtin_amdgcn_mfma_f32_16x16x32_bf16(a, b, c, 0, 0, 0)

// ---- staging helpers (caller syncs) ----

// Ws[g][e] = W16[g*ldw + woff + e]  (row-major bf16 weight, padded rows)
__device__ __forceinline__ void stage_W16(const unsigned short* __restrict__ W16,
                                          int ldw, int woff,
                                          unsigned short (*Ws)[SPAD], int tid)
{
    const int g  = tid >> 1;
    const int c0 = (tid & 1) << 6;
    const unsigned short* src = W16 + (size_t)g * ldw + woff + c0;
    #pragma unroll
    for (int j = 0; j < 64; j += 8)
        *(s16x8*)&Ws[g][c0 + j] = *(const s16x8*)(src + j);
}

// As[r][e] = bf16(A32[(row0+r)*128 + e])   (fp32 source)
__device__ __forceinline__ void stage_A32(const float* __restrict__ A, int row0,
                                          unsigned short (*As)[SPAD], int tid)
{
    const int r  = tid & 63;
    const int c0 = (tid >> 6) << 5;
    int gr = row0 + r; if (gr >= NM) gr = NM - 1;
    const float* ap = A + (size_t)gr * HD + c0;
    #pragma unroll
    for (int j = 0; j < 32; j += 8) {
        s16x8 s;
        #pragma unroll
        for (int q = 0; q < 8; ++q) s[q] = (short)f2b(ap[j + q]);
        *(s16x8*)&As[r][c0 + j] = s;
    }
}

// As[r][e] = A16[(row0+r)*128 + e]   (bf16 source)
__device__ __forceinline__ void stage_A16(const unsigned short* __restrict__ A16, int row0,
                                          unsigned short (*As)[SPAD], int tid)
{
    const int r  = tid & 63;
    const int c0 = (tid >> 6) << 5;
    int gr = row0 + r; if (gr >= NM) gr = NM - 1;
    const unsigned short* ap = A16 + (size_t)gr * HD + c0;
    #pragma unroll
    for (int j = 0; j < 32; j += 8)
        *(s16x8*)&As[r][c0 + j] = *(const s16x8*)(ap + j);
}

// copy LDS rows [0,64) x [0,128) -> global bf16 [row0..][128]
__device__ __forceinline__ void lds_to_g16(const unsigned short (*L)[SPAD], int row0,
                                           unsigned short* __restrict__ G, int tid)
{
    const int r  = tid & 63;
    const int c0 = (tid >> 6) << 5;
    const int gr = row0 + r;
    if (gr >= NM) return;
    #pragma unroll
    for (int j = 0; j < 32; j += 8)
        *(s16x8*)&G[(size_t)gr * HD + c0 + j] = *(const s16x8*)&L[r][c0 + j];
}

// 16x16x32 MFMA sweep: acc[nf] += As[wave rows] @ Ws[cols nf*16..]^T over K=128
__device__ __forceinline__ void mfma_128(const unsigned short (*As)[SPAD],
                                         const unsigned short (*Ws)[SPAD],
                                         int w, int l, fx4 (&acc)[8])
{
    const int rb = w * 16 + (l & 15);
    const int kq = (l >> 4) << 3;
    #pragma unroll
    for (int ks = 0; ks < 4; ++ks) {
        const s16x8 a = *(const s16x8*)&As[rb][ks * 32 + kq];
        #pragma unroll
        for (int nf = 0; nf < 8; ++nf) {
            const s16x8 b = *(const s16x8*)&Ws[nf * 16 + (l & 15)][ks * 32 + kq];
            acc[nf] = MFMA16(a, b, acc[nf]);
        }
    }
}

#define ZACC(acc) { _Pragma("unroll") for (int z_ = 0; z_ < 8; ++z_) \
                    acc[z_] = (fx4)0.0f; }

// ---------- weight fp32 -> bf16 conversion (once per call) ----------
__global__ __launch_bounds__(256)
void dgru_wcvt(const float* __restrict__ Wz, const float* __restrict__ Wr,
               const float* __restrict__ Ur, const float* __restrict__ Wh,
               unsigned short* __restrict__ w16)
{
    const int i = blockIdx.x * 256 + threadIdx.x;
    float v;
    if      (i < 32768) v = Wz[i];
    else if (i < 49152) v = Wr[i - 32768];
    else if (i < 65536) v = Ur[i - 49152];
    else                v = Wh[i - 65536];
    w16[i] = f2b(v);
}

// ---------- pre: pre_z / pre_r / pre_hf + h0 + Uh0 ----------
__global__ __launch_bounds__(256)
void dgru_pre(const float* __restrict__ fmess,
              const unsigned short* __restrict__ wz16,
              const unsigned short* __restrict__ wr16,
              const unsigned short* __restrict__ wh16,
              const unsigned short* __restrict__ ur16,
              const float* __restrict__ bz, const float* __restrict__ bh,
              const float* __restrict__ bur,
              float* __restrict__ pre_z, float* __restrict__ pre_r,
              float* __restrict__ pre_hf,
              unsigned short* __restrict__ h16, unsigned short* __restrict__ uh16)
{
    __shared__ unsigned short As[BM][SPAD];
    __shared__ unsigned short Ws[HD][SPAD];
    const int tid  = threadIdx.x;
    const int row0 = blockIdx.x * BM;
    const int w    = tid >> 6;
    const int l    = tid & 63;

    stage_A32(fmess, row0, As, tid);
    stage_W16(wz16, 2 * HD, 0, Ws, tid);
    __syncthreads();

    fx4 accz[8];
    ZACC(accz);
    mfma_128(As, Ws, w, l, accz);
    #pragma unroll
    for (int nf = 0; nf < 8; ++nf) {
        const int col = nf * 16 + (l & 15);
        const float bv = bz[col];
        #pragma unroll
        for (int q = 0; q < 4; ++q) {
            accz[nf][q] += bv;
            const int gr = row0 + w * 16 + ((l >> 4) << 2) + q;
            if (gr < NM) pre_z[(size_t)gr * HD + col] = accz[nf][q];
        }
    }
    __syncthreads();

    stage_W16(wr16, HD, 0, Ws, tid);
    __syncthreads();
    {
        fx4 acc[8]; ZACC(acc);
        mfma_128(As, Ws, w, l, acc);
        #pragma unroll
        for (int nf = 0; nf < 8; ++nf) {
            const int col = nf * 16 + (l & 15);
            #pragma unroll
            for (int q = 0; q < 4; ++q) {
                const int gr = row0 + w * 16 + ((l >> 4) << 2) + q;
                if (gr < NM) pre_r[(size_t)gr * HD + col] = acc[nf][q];
            }
        }
    }
    __syncthreads();

    stage_W16(wh16, 2 * HD, 0, Ws, tid);
    __syncthreads();
    {
        fx4 acc[8]; ZACC(acc);
        mfma_128(As, Ws, w, l, acc);
        __syncthreads();   // all waves done reading As before h0 overwrite
        #pragma unroll
        for (int nf = 0; nf < 8; ++nf) {
            const int col = nf * 16 + (l & 15);
            const float bv = bh[col];
            #pragma unroll
            for (int q = 0; q < 4; ++q) {
                const int rl = w * 16 + ((l >> 4) << 2) + q;
                const int gr = row0 + rl;
                const float p = acc[nf][q] + bv;
                float h0 = sigm_f(accz[nf][q]) * tanh_f(p);
                if (gr == 0) h0 = 0.0f;
                if (gr < NM) pre_hf[(size_t)gr * HD + col] = p;
                As[rl][col] = f2b(h0);
            }
        }
    }
    stage_W16(ur16, HD, 0, Ws, tid);
    __syncthreads();

    lds_to_g16(As, row0, h16, tid);
    {
        fx4 acc[8]; ZACC(acc);
        mfma_128(As, Ws, w, l, acc);
        __syncthreads();   // all waves done reading Ws before Uh overwrite
        #pragma unroll
        for (int nf = 0; nf < 8; ++nf) {
            const int col = nf * 16 + (l & 15);
            const float bv = bur[col];
            #pragma unroll
            for (int q = 0; q < 4; ++q) {
                const int rl = w * 16 + ((l >> 4) << 2) + q;
                Ws[rl][col] = f2b(acc[nf][q] + bv);
            }
        }
        __syncthreads();
        lds_to_g16(Ws, row0, uh16, tid);
    }
}

// ---------- zh: z-GEMM (z in regs) + h-GEMM/GRU update + next Uh ----------
__global__ __launch_bounds__(256)
void dgru_zh(const unsigned short* __restrict__ sh16,
             const unsigned short* __restrict__ sg16,
             const float* __restrict__ pre_z, const float* __restrict__ pre_hf,
             const unsigned short* __restrict__ wz16,
             const unsigned short* __restrict__ wh16,
             const unsigned short* __restrict__ ur16,
             const float* __restrict__ bur,
             unsigned short* __restrict__ h16, unsigned short* __restrict__ uh16,
             float* __restrict__ hout, int do_uh)
{
    __shared__ unsigned short As[BM][SPAD];
    __shared__ unsigned short Ws[HD][SPAD];
    const int tid  = threadIdx.x;
    const int row0 = blockIdx.x * BM;
    const int w    = tid >> 6;
    const int l    = tid & 63;

    // phase 1: z = sigmoid(pre_z + sum_h @ Wz2.T)   (registers only)
    stage_A16(sh16, row0, As, tid);
    stage_W16(wz16, 2 * HD, HD, Ws, tid);
    __syncthreads();
    fx4 zres[8];
    {
        fx4 acc[8]; ZACC(acc);
        mfma_128(As, Ws, w, l, acc);
        #pragma unroll
        for (int nf = 0; nf < 8; ++nf) {
            const int col = nf * 16 + (l & 15);
            #pragma unroll
            for (int q = 0; q < 4; ++q) {
                int gr = row0 + w * 16 + ((l >> 4) << 2) + q;
                if (gr >= NM) gr = NM - 1;
                zres[nf][q] = sigm_f(pre_z[(size_t)gr * HD + col] + acc[nf][q]);
            }
        }
    }
    __syncthreads();

    // phase 2: ph = tanh(pre_hf + sum_g @ Wh2.T); h = (1-z)*sum_h + z*ph
    stage_A16(sg16, row0, As, tid);
    stage_W16(wh16, 2 * HD, HD, Ws, tid);
    __syncthreads();
    {
        fx4 acc[8]; ZACC(acc);
        mfma_128(As, Ws, w, l, acc);
        __syncthreads();   // As readers done before h overwrite
        #pragma unroll
        for (int nf = 0; nf < 8; ++nf) {
            const int col = nf * 16 + (l & 15);
            #pragma unroll
            for (int q = 0; q < 4; ++q) {
                const int rl = w * 16 + ((l >> 4) << 2) + q;
                const int gr = row0 + rl;
                const int cr = (gr < NM) ? gr : (NM - 1);
                const size_t off = (size_t)cr * HD + col;
                const float p  = pre_hf[off];
                const float sh = b2f(sh16[off]);
                const float zz = zres[nf][q];
                float o = (1.0f - zz) * sh + zz * tanh_f(p + acc[nf][q]);
                if (gr == 0) o = 0.0f;
                if (do_uh) {
                    As[rl][col] = f2b(o);
                } else if (gr < NM) {
                    hout[off] = o;
                }
            }
        }
    }
    if (!do_uh) return;

    // phase 3: Uh = h @ Ur.T + bur
    stage_W16(ur16, HD, 0, Ws, tid);
    __syncthreads();
    lds_to_g16(As, row0, h16, tid);
    {
        fx4 acc[8]; ZACC(acc);
        mfma_128(As, Ws, w, l, acc);
        __syncthreads();   // Ws readers done before Uh overwrite
        #pragma unroll
        for (int nf = 0; nf < 8; ++nf) {
            const int col = nf * 16 + (l & 15);
            const float bv = bur[col];
            #pragma unroll
            for (int q = 0; q < 4; ++q) {
                const int rl = w * 16 + ((l >> 4) << 2) + q;
                Ws[rl][col] = f2b(acc[nf][q] + bv);
            }
        }
        __syncthreads();
        lds_to_g16(Ws, row0, uh16, tid);
    }
}

// ---------- gather (bf16 h/Uh, fp32 accumulate, bf16 sums out) ----------
__global__ __launch_bounds__(256)
void dgru_gather(const unsigned short* __restrict__ h16,
                 const unsigned short* __restrict__ uh16,
                 const int* __restrict__ bgraph, const float* __restrict__ pre_r,
                 unsigned short* __restrict__ sh16, unsigned short* __restrict__ sg16)
{
    const int tid = threadIdx.x;
    const int n   = blockIdx.x * 8 + (tid >> 5);
    const int d0  = (tid & 31) << 2;

    const int4* bg = (const int4*)(bgraph + (size_t)n * KNEI);
    const int4 b0 = bg[0], b1 = bg[1];
    const int idx[KNEI] = {b0.x, b0.y, b0.z, b0.w, b1.x, b1.y, b1.z, b1.w};

    s16x4 hr[KNEI], ur[KNEI];
    #pragma unroll
    for (int k = 0; k < KNEI; ++k)
        hr[k] = *(const s16x4*)&h16[(size_t)idx[k] * HD + d0];
    #pragma unroll
    for (int k = 0; k < KNEI; ++k)
        ur[k] = *(const s16x4*)&uh16[(size_t)idx[k] * HD + d0];
    const fx4 pr = *(const fx4*)&pre_r[(size_t)n * HD + d0];

    float sh[4] = {0.f, 0.f, 0.f, 0.f};
    float sg[4] = {0.f, 0.f, 0.f, 0.f};
    #pragma unroll
    for (int k = 0; k < KNEI; ++k) {
        #pragma unroll
        for (int j = 0; j < 4; ++j) {
            const float hv = b2f((unsigned short)hr[k][j]);
            const float uv = b2f((unsigned short)ur[k][j]);
            sh[j] += hv;
            sg[j] = fmaf(sigm_f(pr[j] + uv), hv, sg[j]);
        }
    }
    s16x4 osh, osg;
    #pragma unroll
    for (int j = 0; j < 4; ++j) {
        osh[j] = (short)f2b(sh[j]);
        osg[j] = (short)f2b(sg[j]);
    }
    const size_t o = (size_t)n * HD + d0;
    *(s16x4*)&sh16[o] = osh;
    *(s16x4*)&sg16[o] = osg;
}

extern "C" void kernel_launch(void* const* d_in, const int* in_sizes, int n_in,
                              void* d_out, int out_size, void* d_ws, size_t ws_size,
                              hipStream_t stream) {
    const float* fmess  = (const float*)d_in[0];
    const int*   bgraph = (const int*)  d_in[1];
    const float* W_z    = (const float*)d_in[2];
    const float* b_z    = (const float*)d_in[3];
    const float* W_r    = (const float*)d_in[4];
    const float* U_r    = (const float*)d_in[5];
    const float* b_Ur   = (const float*)d_in[6];
    const float* W_h    = (const float*)d_in[7];
    const float* b_h    = (const float*)d_in[8];

    float* ws = (float*)d_ws;
    float* pre_z  = ws;
    float* pre_r  = ws + NH;
    float* pre_hf = ws + 2 * NH;
    unsigned short* h16  = (unsigned short*)(ws + 3 * NH);
    unsigned short* uh16 = h16 + NH;
    unsigned short* sh16 = (unsigned short*)(ws + 4 * NH);
    unsigned short* sg16 = sh16 + NH;
    unsigned short* w16  = (unsigned short*)(ws + 5 * NH);
    unsigned short* wz16 = w16;            // [128][256]
    unsigned short* wr16 = w16 + 32768;    // [128][128]
    unsigned short* ur16 = w16 + 49152;    // [128][128]
    unsigned short* wh16 = w16 + 65536;    // [128][256]
    float* hout = (float*)d_out;
    // ws usage: 5*NH*4 + 196608 B ~= 128.2 MB (prior rounds used 153.6 OK)

    dgru_wcvt<<<dim3(384), dim3(256), 0, stream>>>(W_z, W_r, U_r, W_h, w16);

    dgru_pre<<<dim3(NBLK), dim3(256), 0, stream>>>(
        fmess, wz16, wr16, wh16, ur16, b_z, b_h, b_Ur,
        pre_z, pre_r, pre_hf, h16, uh16);

    for (int it = 1; it < 5; ++it) {
        dgru_gather<<<dim3(NM / 8), dim3(256), 0, stream>>>(
            h16, uh16, bgraph, pre_r, sh16, sg16);
        dgru_zh<<<dim3(NBLK), dim3(256), 0, stream>>>(
            sh16, sg16, pre_z, pre_hf, wz16, wh16, ur16, b_Ur,
            h16, uh16, hout, (it < 4) ? 1 : 0);
    }
}